// Round 1
// baseline (452.055 us; speedup 1.0000x reference)
//
#include <hip/hip_runtime.h>
#include <math.h>

#define EPSF 1.1920928955078125e-07f  // np.float32 eps

constexpr int B_ = 16, S_ = 8, CH = 3, K_ = 6;
constexpr int P_ = 128 * 128;          // pixels per image
constexpr int NCH = 32;                // chunks per image
constexpr int CPIX = P_ / NCH;         // 512 pixels per chunk
constexpr int TILE = 128;              // LDS staging tile (pixels)
constexpr int NF1 = 106;               // per-k reduce1 sums: 96 ops_first + 10 sym M2
constexpr int NF2 = 48;                // per-k reduce2 sums: 8 s * 6 sym sigma

// ---------------------------------------------------------------- softmax (step 0)
__global__ __launch_bounds__(256) void k_softmax0(const float* __restrict__ pred,
                                                  float* __restrict__ gp) {
  int g = blockIdx.x * 256 + threadIdx.x;       // over B_*P_
  int u = g >> 14, p = g & (P_ - 1);
  const float* pr = pred + ((size_t)u * K_) * P_ + p;
  float l[K_];
  float mx = -1e30f;
#pragma unroll
  for (int k = 0; k < K_; k++) { l[k] = pr[(size_t)k * P_]; mx = fmaxf(mx, l[k]); }
  float s = 0.f;
#pragma unroll
  for (int k = 0; k < K_; k++) { l[k] = expf(l[k] - mx); s += l[k]; }
  float inv = 1.f / s;
  float* gw = gp + ((size_t)u * K_) * P_ + p;
#pragma unroll
  for (int k = 0; k < K_; k++) gw[(size_t)k * P_] = l[k] * inv + EPSF;
}

// ---------------------------------------------------------------- 4x4 inverse (Gauss-Jordan, PD + eps, no pivot)
__device__ __forceinline__ void inv4(const float* Ain, float* out) {
  float a[4][8];
#pragma unroll
  for (int i = 0; i < 4; i++) {
#pragma unroll
    for (int j = 0; j < 4; j++) { a[i][j] = Ain[i * 4 + j]; a[i][4 + j] = (i == j) ? 1.f : 0.f; }
  }
#pragma unroll
  for (int c = 0; c < 4; c++) {
    float piv = 1.f / a[c][c];
#pragma unroll
    for (int j = 0; j < 8; j++) a[c][j] *= piv;
#pragma unroll
    for (int r = 0; r < 4; r++) {
      if (r != c) {
        float f = a[r][c];
#pragma unroll
        for (int j = 0; j < 8; j++) a[r][j] -= f * a[c][j];
      }
    }
  }
#pragma unroll
  for (int i = 0; i < 4; i++)
#pragma unroll
    for (int j = 0; j < 4; j++) out[i * 4 + j] = a[i][4 + j];
}

// ---------------------------------------------------------------- reduce1: moments per (u,k)
// block = (u, chunk), 384 threads = 6 waves, wave w handles k=w.
__global__ __launch_bounds__(384) void k_reduce1(const float* __restrict__ img,
                                                 const float* __restrict__ shf,
                                                 const float* __restrict__ gp,
                                                 float* __restrict__ p1) {
  __shared__ float stg[TILE * 27];
  int u = blockIdx.x / NCH, ch = blockIdx.x % NCH;
  int tid = threadIdx.x;
  int k = tid >> 6, lane = tid & 63;

  const float* imgu = img + (size_t)u * CH * P_;
  const float* shfu = shf + (size_t)u * S_ * CH * P_;
  const float* gpu = gp + ((size_t)(u * K_ + k)) * P_;

  float acc[NF1];
#pragma unroll
  for (int i = 0; i < NF1; i++) acc[i] = 0.f;

  for (int t = 0; t < CPIX / TILE; t++) {
    int tp0 = ch * CPIX + t * TILE;
    for (int e = tid; e < 27 * TILE; e += 384) {
      int c = e >> 7, pix = e & (TILE - 1);
      stg[pix * 27 + c] = (c < CH) ? imgu[c * P_ + tp0 + pix]
                                   : shfu[(c - CH) * P_ + tp0 + pix];
    }
    __syncthreads();
#pragma unroll
    for (int rep = 0; rep < TILE / 64; rep++) {
      int pix = lane + rep * 64;
      const float* L = &stg[pix * 27];
      float i0 = L[0], i1 = L[1], i2 = L[2];
      float gpv = gpu[tp0 + pix];
      float t0 = gpv * i0, t1 = gpv * i1, t2 = gpv * i2, t3 = gpv;
      // ops_first: F[s][a][b] += shifted[s][a] * gp * padded[b]
#pragma unroll
      for (int s = 0; s < S_; s++) {
#pragma unroll
        for (int a = 0; a < CH; a++) {
          float sv = L[3 + s * 3 + a];
          int base = (s * 3 + a) * 4;
          acc[base + 0] += sv * t0;
          acc[base + 1] += sv * t1;
          acc[base + 2] += sv * t2;
          acc[base + 3] += sv * t3;
        }
      }
      // M2 sym: (0,0)(0,1)(0,2)(0,3)(1,1)(1,2)(1,3)(2,2)(2,3)(3,3)
      acc[96 + 0] += i0 * t0; acc[96 + 1] += i0 * t1; acc[96 + 2] += i0 * t2; acc[96 + 3] += t0;
      acc[96 + 4] += i1 * t1; acc[96 + 5] += i1 * t2; acc[96 + 6] += t1;
      acc[96 + 7] += i2 * t2; acc[96 + 8] += t2;      acc[96 + 9] += t3;
    }
    __syncthreads();
  }
  // wave reduction (deterministic), lane0 writes chunk partials
#pragma unroll
  for (int i = 0; i < NF1; i++) {
    float v = acc[i];
    for (int off = 32; off > 0; off >>= 1) v += __shfl_xor(v, off, 64);
    acc[i] = v;
  }
  if (lane == 0) {
    float* dst = p1 + ((size_t)(u * K_ + k) * NCH + ch) * NF1;
#pragma unroll
    for (int i = 0; i < NF1; i++) dst[i] = acc[i];
  }
}

// ---------------------------------------------------------------- reduce2: sigma sums per (u,s,k)
__global__ __launch_bounds__(384) void k_reduce2(const float* __restrict__ img,
                                                 const float* __restrict__ shf,
                                                 const float* __restrict__ gp,
                                                 const float* __restrict__ p1,
                                                 float* __restrict__ p2) {
  __shared__ float stg[TILE * 27];
  __shared__ float sum1[K_ * NF1];
  __shared__ float invA[K_ * 16];
  __shared__ float normL[K_];
  __shared__ float pnL[K_];
  __shared__ float opsL[K_ * 96];

  int u = blockIdx.x / NCH, ch = blockIdx.x % NCH;
  int tid = threadIdx.x;

  // fixed-order sum over chunk partials
  for (int e = tid; e < K_ * NF1; e += 384) {
    int k = e / NF1, i = e % NF1;
    const float* src = p1 + ((size_t)(u * K_ + k) * NCH) * NF1 + i;
    float s = 0.f;
    for (int c2 = 0; c2 < NCH; c2++) s += src[c2 * NF1];
    sum1[e] = s;
  }
  __syncthreads();
  if (tid < K_) {  // solve1: invert normalized 4x4
    int k = tid;
    const float* m = &sum1[k * NF1 + 96];
    float tr = m[0] + m[4] + m[7] + m[9];
    float nrm = 1.f / tr;
    normL[k] = nrm;
    pnL[k] = 1.f / m[9];  // M2[3][3] = sum gp
    const int sym[4][4] = {{0, 1, 2, 3}, {1, 4, 5, 6}, {2, 5, 7, 8}, {3, 6, 8, 9}};
    float A[16];
#pragma unroll
    for (int i = 0; i < 4; i++)
#pragma unroll
      for (int j = 0; j < 4; j++)
        A[i * 4 + j] = m[sym[i][j]] * nrm + ((i == j) ? EPSF : 0.f);
    inv4(A, &invA[k * 16]);
  }
  __syncthreads();
  // ops[k][s][a][b] = norm * sum_c F[k][s][a][c] * invA[k][c][b]
  for (int e = tid; e < K_ * 96; e += 384) {
    int k = e / 96, r = e % 96;
    int sa = r >> 2, bcol = r & 3;
    float v = 0.f;
#pragma unroll
    for (int c = 0; c < 4; c++) v += sum1[k * NF1 + sa * 4 + c] * invA[k * 16 + c * 4 + bcol];
    opsL[e] = v * normL[k];
  }
  __syncthreads();

  int k = tid >> 6, lane = tid & 63;
  float opr[96];
#pragma unroll
  for (int i = 0; i < 96; i++) opr[i] = opsL[k * 96 + i];
  float pn = pnL[k];
  const float* imgu = img + (size_t)u * CH * P_;
  const float* shfu = shf + (size_t)u * S_ * CH * P_;
  const float* gpu = gp + ((size_t)(u * K_ + k)) * P_;

  float acc[NF2];
#pragma unroll
  for (int j = 0; j < NF2; j++) acc[j] = 0.f;

  for (int t = 0; t < CPIX / TILE; t++) {
    int tp0 = ch * CPIX + t * TILE;
    for (int e = tid; e < 27 * TILE; e += 384) {
      int c = e >> 7, pix = e & (TILE - 1);
      stg[pix * 27 + c] = (c < CH) ? imgu[c * P_ + tp0 + pix]
                                   : shfu[(c - CH) * P_ + tp0 + pix];
    }
    __syncthreads();
#pragma unroll
    for (int rep = 0; rep < TILE / 64; rep++) {
      int pix = lane + rep * 64;
      const float* L = &stg[pix * 27];
      float i0 = L[0], i1 = L[1], i2 = L[2];
      float pp = gpu[tp0 + pix] * pn;
#pragma unroll
      for (int s = 0; s < S_; s++) {
        const float* o = &opr[s * 12];
        float d0 = L[3 + s * 3 + 0] - (o[0] * i0 + o[1] * i1 + o[2] * i2 + o[3]);
        float d1 = L[3 + s * 3 + 1] - (o[4] * i0 + o[5] * i1 + o[6] * i2 + o[7]);
        float d2 = L[3 + s * 3 + 2] - (o[8] * i0 + o[9] * i1 + o[10] * i2 + o[11]);
        float q0 = pp * d0, q1 = pp * d1, q2 = pp * d2;
        int base = s * 6;
        acc[base + 0] += q0 * d0; acc[base + 1] += q0 * d1; acc[base + 2] += q0 * d2;
        acc[base + 3] += q1 * d1; acc[base + 4] += q1 * d2; acc[base + 5] += q2 * d2;
      }
    }
    __syncthreads();
  }
#pragma unroll
  for (int j = 0; j < NF2; j++) {
    float v = acc[j];
    for (int off = 32; off > 0; off >>= 1) v += __shfl_xor(v, off, 64);
    acc[j] = v;
  }
  if (lane == 0) {
    float* dst = p2 + ((size_t)(u * K_ + k) * NCH + ch) * NF2;
#pragma unroll
    for (int j = 0; j < NF2; j++) dst[j] = acc[j];
  }
}

// ---------------------------------------------------------------- e-step (+ next softmax fused)
template <int LAST>
__global__ __launch_bounds__(384) void k_estep(const float* __restrict__ img,
                                               const float* __restrict__ shf,
                                               const float* __restrict__ pred,
                                               const float* __restrict__ p1,
                                               const float* __restrict__ p2,
                                               float* __restrict__ out,
                                               float* __restrict__ gp) {
  __shared__ float stg[TILE * 27];
  __shared__ float gmL[TILE * K_];
  __shared__ float sum1[K_ * NF1];
  __shared__ float invA[K_ * 16];
  __shared__ float normL[K_];
  __shared__ float opsL[K_ * 96];
  __shared__ float sigL[K_ * NF2];
  __shared__ float sinvL[K_ * S_ * 6];
  __shared__ float ldetL[K_ * S_];
  __shared__ float ldsumL[K_];

  int u = blockIdx.x / NCH, ch = blockIdx.x % NCH;
  int tid = threadIdx.x;

  for (int e = tid; e < K_ * NF1; e += 384) {
    int k = e / NF1, i = e % NF1;
    const float* src = p1 + ((size_t)(u * K_ + k) * NCH) * NF1 + i;
    float s = 0.f;
    for (int c2 = 0; c2 < NCH; c2++) s += src[c2 * NF1];
    sum1[e] = s;
  }
  for (int e = tid; e < K_ * NF2; e += 384) {
    int k = e / NF2, j = e % NF2;
    const float* src = p2 + ((size_t)(u * K_ + k) * NCH) * NF2 + j;
    float s = 0.f;
    for (int c2 = 0; c2 < NCH; c2++) s += src[c2 * NF2];
    sigL[e] = s;
  }
  __syncthreads();
  if (tid < K_) {  // wave0: solve1
    int k = tid;
    const float* m = &sum1[k * NF1 + 96];
    float tr = m[0] + m[4] + m[7] + m[9];
    float nrm = 1.f / tr;
    normL[k] = nrm;
    const int sym[4][4] = {{0, 1, 2, 3}, {1, 4, 5, 6}, {2, 5, 7, 8}, {3, 6, 8, 9}};
    float A[16];
#pragma unroll
    for (int i = 0; i < 4; i++)
#pragma unroll
      for (int j = 0; j < 4; j++)
        A[i * 4 + j] = m[sym[i][j]] * nrm + ((i == j) ? EPSF : 0.f);
    inv4(A, &invA[k * 16]);
  } else if (tid >= 64 && tid < 64 + K_ * S_) {  // wave1: solve2 (3x3 inverse + logdet)
    int t = tid - 64;  // t = k*8+s
    int base = (t / S_) * NF2 + (t % S_) * 6;
    float a = sigL[base + 0] + EPSF, b = sigL[base + 1], c = sigL[base + 2];
    float d = sigL[base + 3] + EPSF, e = sigL[base + 4], f = sigL[base + 5] + EPSF;
    float c00 = d * f - e * e, c01 = c * e - b * f, c02 = b * e - c * d;
    float det = a * c00 + b * c01 + c * c02;
    float id = 1.f / det;
    sinvL[t * 6 + 0] = c00 * id;
    sinvL[t * 6 + 1] = c01 * id;
    sinvL[t * 6 + 2] = c02 * id;
    sinvL[t * 6 + 3] = (a * f - c * c) * id;
    sinvL[t * 6 + 4] = (c * b - a * e) * id;
    sinvL[t * 6 + 5] = (a * d - b * b) * id;
    ldetL[t] = logf(det);
  }
  __syncthreads();
  for (int e = tid; e < K_ * 96; e += 384) {
    int k = e / 96, r = e % 96;
    int sa = r >> 2, bcol = r & 3;
    float v = 0.f;
#pragma unroll
    for (int c = 0; c < 4; c++) v += sum1[k * NF1 + sa * 4 + c] * invA[k * 16 + c * 4 + bcol];
    opsL[e] = v * normL[k];
  }
  if (tid < K_) {
    float s = 0.f;
#pragma unroll
    for (int si = 0; si < S_; si++) s += ldetL[tid * S_ + si];
    ldsumL[tid] = s;
  }
  __syncthreads();

  int k = tid >> 6, lane = tid & 63;
  float opr[96];
#pragma unroll
  for (int i = 0; i < 96; i++) opr[i] = opsL[k * 96 + i];
  float ldsum_k = ldsumL[k];
  const float* imgu = img + (size_t)u * CH * P_;
  const float* shfu = shf + (size_t)u * S_ * CH * P_;
  const float* predu = pred + (size_t)u * K_ * P_;
  float* outu = out + (size_t)u * K_ * P_;
  float* gpu = gp + (size_t)u * K_ * P_;

  for (int t = 0; t < CPIX / TILE; t++) {
    int tp0 = ch * CPIX + t * TILE;
    for (int e = tid; e < 27 * TILE; e += 384) {
      int c = e >> 7, pix = e & (TILE - 1);
      stg[pix * 27 + c] = (c < CH) ? imgu[c * P_ + tp0 + pix]
                                   : shfu[(c - CH) * P_ + tp0 + pix];
    }
    __syncthreads();
#pragma unroll
    for (int rep = 0; rep < TILE / 64; rep++) {
      int pix = lane + rep * 64;
      const float* L = &stg[pix * 27];
      float i0 = L[0], i1 = L[1], i2 = L[2];
      float q = 0.f;
#pragma unroll
      for (int s = 0; s < S_; s++) {
        const float* o = &opr[s * 12];
        float d0 = L[3 + s * 3 + 0] - (o[0] * i0 + o[1] * i1 + o[2] * i2 + o[3]);
        float d1 = L[3 + s * 3 + 1] - (o[4] * i0 + o[5] * i1 + o[6] * i2 + o[7]);
        float d2 = L[3 + s * 3 + 2] - (o[8] * i0 + o[9] * i1 + o[10] * i2 + o[11]);
        const float* si = &sinvL[(k * S_ + s) * 6];
        q += si[0] * d0 * d0 + si[3] * d1 * d1 + si[5] * d2 * d2 +
             2.f * (si[1] * d0 * d1 + si[2] * d0 * d2 + si[4] * d1 * d2);
      }
      float gm = -0.5f * q - 0.5f * ldsum_k;
      outu[(size_t)k * P_ + tp0 + pix] = gm;
      if (!LAST) gmL[pix * K_ + k] = gm;
    }
    __syncthreads();
    if (!LAST) {
      if (tid < TILE) {
        int p = tp0 + tid;
        float l[K_];
        float mx = -1e30f;
#pragma unroll
        for (int k2 = 0; k2 < K_; k2++) {
          l[k2] = predu[(size_t)k2 * P_ + p] + gmL[tid * K_ + k2];
          mx = fmaxf(mx, l[k2]);
        }
        float ssum = 0.f;
#pragma unroll
        for (int k2 = 0; k2 < K_; k2++) { l[k2] = expf(l[k2] - mx); ssum += l[k2]; }
        float inv = 1.f / ssum;
#pragma unroll
        for (int k2 = 0; k2 < K_; k2++) gpu[(size_t)k2 * P_ + p] = l[k2] * inv + EPSF;
      }
      __syncthreads();
    }
  }
}

// ---------------------------------------------------------------- launch
extern "C" void kernel_launch(void* const* d_in, const int* in_sizes, int n_in,
                              void* d_out, int out_size, void* d_ws, size_t ws_size,
                              hipStream_t stream) {
  const float* img = (const float*)d_in[0];   // [B,3,128,128]
  const float* shf = (const float*)d_in[1];   // [B,8,3,128,128]
  const float* pred = (const float*)d_in[2];  // [B,6,128,128]
  float* out = (float*)d_out;                 // [B,6,128,128]
  float* wsf = (float*)d_ws;
  float* gp = wsf;                                   // B*K*P
  float* p1 = gp + (size_t)B_ * K_ * P_;             // B*K*NCH*NF1
  float* p2 = p1 + (size_t)B_ * K_ * NCH * NF1;      // B*K*NCH*NF2

  k_softmax0<<<(B_ * P_) / 256, 256, 0, stream>>>(pred, gp);
  for (int step = 0; step < 3; step++) {
    k_reduce1<<<B_ * NCH, 384, 0, stream>>>(img, shf, gp, p1);
    k_reduce2<<<B_ * NCH, 384, 0, stream>>>(img, shf, gp, p1, p2);
    if (step < 2)
      k_estep<0><<<B_ * NCH, 384, 0, stream>>>(img, shf, pred, p1, p2, out, gp);
    else
      k_estep<1><<<B_ * NCH, 384, 0, stream>>>(img, shf, pred, p1, p2, out, gp);
  }
}